// Round 4
// baseline (83.484 us; speedup 1.0000x reference)
//
#include <hip/hip_runtime.h>

// Problem constants (fixed by setup_inputs): B=16, N=3000, M=300, L=80, K=4
#define BB 16
#define NN 3000
#define MM 300
#define LL 80
#define KK 4
#define IOU_THRESH 0.6f

typedef unsigned long long u64;

struct Box { float x1, y1, x2, y2, area; };

__device__ __forceinline__ Box to_xyxy(float4 b) {
#pragma clang fp contract(off)
    Box r;
    r.x1 = b.x - 0.5f * b.z;
    r.y1 = b.y - 0.5f * b.w;
    r.x2 = b.x + 0.5f * b.z;
    r.y2 = b.y + 0.5f * b.w;
    r.area = (r.x2 - r.x1) * (r.y2 - r.y1);
    return r;
}

// Same inlined function used in both the top phase and the asn phase (the
// lq test relies on bitwise-identical iou; same argument order everywhere).
__device__ __forceinline__ float pair_iou(Box a, Box b) {
#pragma clang fp contract(off)
    float ltx = fmaxf(a.x1, b.x1);
    float lty = fmaxf(a.y1, b.y1);
    float rbx = fminf(a.x2, b.x2);
    float rby = fminf(a.y2, b.y2);
    float wx = fmaxf(rbx - ltx, 0.0f);
    float wy = fmaxf(rby - lty, 0.0f);
    float inter = wx * wy;
    float uni = a.area + b.area - inter;
    return inter / fmaxf(uni, 1e-9f);
}

// monotonic float <-> u32 (order-preserving bijection, finite values)
__device__ __forceinline__ unsigned int f32_to_ordered(float f) {
    unsigned int u = __float_as_uint(f);
    return (u & 0x80000000u) ? ~u : (u | 0x80000000u);
}
__device__ __forceinline__ float ordered_to_f32(unsigned int u) {
    unsigned int b = (u & 0x80000000u) ? (u & 0x7FFFFFFFu) : ~u;
    return __uint_as_float(b);
}

__device__ __forceinline__ u64 umax64(u64 a, u64 b) { return a > b ? a : b; }
__device__ __forceinline__ u64 umin64(u64 a, u64 b) { return a < b ? a : b; }

__device__ __forceinline__ u64 shfl_xor_u64(u64 v, int mask) {
    int lo = __shfl_xor((int)(unsigned)v, mask, 64);
    int hi = __shfl_xor((int)(unsigned)(v >> 32), mask, 64);
    return ((u64)(unsigned)hi << 32) | (u64)(unsigned)lo;
}

// branchless insert of k into sorted-desc 4-list
__device__ __forceinline__ void topins(u64 t[4], u64 k) {
    u64 c0 = umin64(t[0], k);
    t[0] = umax64(t[0], k);
    u64 c1 = umin64(t[1], c0);
    t[1] = umax64(t[1], c0);
    u64 c2 = umin64(t[2], c1);
    t[2] = umax64(t[2], c1);
    t[3] = umax64(t[3], c2);
}

// butterfly: top-4 of the union of all 64 lanes' sorted-desc 4-lists (all lanes get result)
__device__ __forceinline__ void wave_merge_top4(u64 t[4]) {
    #pragma unroll
    for (int s = 1; s < 64; s <<= 1) {
        u64 b0 = shfl_xor_u64(t[0], s);
        u64 b1 = shfl_xor_u64(t[1], s);
        u64 b2 = shfl_xor_u64(t[2], s);
        u64 b3 = shfl_xor_u64(t[3], s);
        u64 a0 = t[0], a1 = t[1], a2 = t[2], a3 = t[3];
        t[0] = umax64(a0, b0);
        t[1] = umax64(umin64(a0, b0), umax64(a1, b1));
        t[2] = umax64(umax64(a2, b2), umax64(umin64(a0, b1), umin64(a1, b0)));
        t[3] = umax64(umax64(a3, b3),
               umax64(umin64(a0, b2), umax64(umin64(a1, b1), umin64(a2, b0))));
    }
}

// ---------------------------------------------------------------------------
// kPrep: one block per batch (16 x 512). Label-histogram + exclusive prefix +
// scatter of proposal indices and GT row indices into per-label buckets.
// Verbatim structure from the R0-verified kBin (just 512 threads, no counts).
// Bucket order is nondeterministic (LDS atomic cursors) but all downstream
// results are order-invariant (exact u64-key max with index tie-breaks).
// ---------------------------------------------------------------------------
__global__ __launch_bounds__(512) void kPrep(const int* __restrict__ pinds,
                                             const int* __restrict__ glab,
                                             unsigned short* __restrict__ pidx,
                                             int* __restrict__ pstart,
                                             int* __restrict__ pcnt,
                                             unsigned short* __restrict__ gidx,
                                             int* __restrict__ gstart,
                                             int* __restrict__ gcnt) {
    int b = blockIdx.x;
    int tid = threadIdx.x;
    __shared__ int hist[LL], cur[LL], gh[LL], gcur[LL];
    if (tid < LL) { hist[tid] = 0; gh[tid] = 0; }
    __syncthreads();
    for (int n = tid; n < NN; n += 512) atomicAdd(&hist[pinds[b * NN + n]], 1);
    for (int m = tid; m < MM; m += 512) atomicAdd(&gh[glab[b * MM + m]], 1);
    __syncthreads();
    if (tid < LL) {
        int s = 0;
        for (int j = 0; j < tid; ++j) s += hist[j];
        cur[tid] = s; pstart[b * LL + tid] = s; pcnt[b * LL + tid] = hist[tid];
        int t = 0;
        for (int j = 0; j < tid; ++j) t += gh[j];
        gcur[tid] = t; gstart[b * LL + tid] = t; gcnt[b * LL + tid] = gh[tid];
    }
    __syncthreads();
    for (int n = tid; n < NN; n += 512) {
        int l = pinds[b * NN + n];
        int pos = atomicAdd(&cur[l], 1);
        pidx[b * NN + pos] = (unsigned short)n;
    }
    for (int m = tid; m < MM; m += 512) {
        int l = glab[b * MM + m];
        int pos = atomicAdd(&gcur[l], 1);
        gidx[b * MM + pos] = (unsigned short)m;
    }
}

// ===========================================================================
// kBuck: ONE block per (label, batch) bucket — grid (80, 16), 256 threads.
// No scanning: loads its precomputed bucket lists (~37 proposals, ~4 GT rows)
// and runs top -> asn -> epilogue with block-local syncs (phases verbatim from
// the R3-verified kFused). GT xyxy/area/gmax are staged in LDS by the top
// phase; asn reuses the exact same bits, preserving the iou==gmax exactness.
// Every (b,m) output slot is written exactly once, by the unique bucket
// (glab[b][m], b); buckets with no GT rows own no slots and return early.
// d_out layout: 4 chunks of BB*MM float4: rows | cols | valid | sel.
// ===========================================================================
__global__ __launch_bounds__(256) void kBuck(
    const float4* __restrict__ props, const float4* __restrict__ gbox,
    const unsigned short* __restrict__ pidx, const int* __restrict__ pstart,
    const int* __restrict__ pcnt, const unsigned short* __restrict__ gidx,
    const int* __restrict__ gstart, const int* __restrict__ gcnt,
    float* __restrict__ out)
{
    const int l = blockIdx.x;   // label
    const int b = blockIdx.y;   // batch
    const int tid = threadIdx.x;

    __shared__ unsigned short plistS[NN];  // bucket proposal indices (worst-case safe)
    __shared__ unsigned short glistS[MM];  // bucket GT row indices
    __shared__ float4 gxyS[MM];            // staged GT xyxy (bits from top phase)
    __shared__ float  gareaS[MM];          // staged GT area
    __shared__ float  gmaxS[MM];           // per-row gmax
    __shared__ float  tvL[MM * KK];        // per-row top-4 values
    __shared__ int    tiL[MM * KK];        // per-row top-4 indices
    __shared__ int    cntsL[MM];           // per-row pos counts

    const int cg_ = gcnt[b * LL + l];
    if (cg_ == 0) return;   // bucket owns no output rows
    const int cp_ = pcnt[b * LL + l];
    const int gs  = gstart[b * LL + l];
    const int ps  = pstart[b * LL + l];

    for (int i = tid; i < cp_; i += 256) plistS[i] = pidx[b * NN + ps + i];
    for (int j = tid; j < cg_; j += 256) { glistS[j] = gidx[b * MM + gs + j]; cntsL[j] = 0; }
    __syncthreads();

    // ---- top: one wave per bucket GT row. Exact lax.top_k top-4 (value desc,
    //      min-index tie-break) + gmax. Slots beyond cp_ stay at init and are
    //      always masked downstream (take <= counts <= cp_).
    {
        const int lane = tid & 63;
        const int wv = tid >> 6;
        for (int j = wv; j < cg_; j += 4) {
            int m = glistS[j];
            Box gt = to_xyxy(gbox[b * MM + m]);
            const u64 init = ((u64)f32_to_ordered(-1.0f) << 32);
            u64 t[4] = {init, init, init, init};
            for (int i = lane; i < cp_; i += 64) {   // cp_ ~ 37, one pass
                int n = plistS[i];
                Box pb = to_xyxy(props[(size_t)b * NN + n]);
                float iou = pair_iou(gt, pb);        // all bucket entries match
                u64 key = ((u64)f32_to_ordered(iou) << 32) |
                          (u64)(0xFFFFFFFFu - (unsigned)n);
                topins(t, key);
            }
            wave_merge_top4(t);
            if (lane == 0) {
                #pragma unroll
                for (int q = 0; q < KK; ++q) {
                    tvL[j * KK + q] = ordered_to_f32((unsigned)(t[q] >> 32));
                    tiL[j * KK + q] = (int)(0xFFFFFFFFu - (unsigned)t[q]);
                }
                gmaxS[j] = ordered_to_f32((unsigned)(t[0] >> 32));
                gxyS[j] = make_float4(gt.x1, gt.y1, gt.x2, gt.y2);
                gareaS[j] = gt.area;
            }
        }
    }
    __syncthreads();

    // ---- asn: one thread per bucket proposal. best_gt = argmax over bucket
    //      GT rows with min-global-m tie-break (matches argmax over all M rows:
    //      non-matching rows are -1 < any iou >= 0); lq via exact iou == gmax.
    for (int p = tid; p < cp_; p += 256) {
        int n = plistS[p];
        Box pb = to_xyxy(props[(size_t)b * NN + n]);
        u64 key = 0;
        int bestj = 0;
        bool lq = false;
        for (int j = 0; j < cg_; ++j) {
            float4 q = gxyS[j];
            Box a; a.x1 = q.x; a.y1 = q.y; a.x2 = q.z; a.y2 = q.w; a.area = gareaS[j];
            float iou = pair_iou(a, pb);   // same bits/arg order as top phase
            int m = glistS[j];
            u64 k = ((u64)f32_to_ordered(iou) << 32) |
                    (u64)(0xFFFFFFFFu - (unsigned)m);
            if (k > key) { key = k; bestj = j; }  // distinct m -> never equal
            lq = lq || (iou == gmaxS[j]);
        }
        // cg_ >= 1 so key was set (iou >= 0 -> k >= 2^63 > 0)
        float v = ordered_to_f32((unsigned)(key >> 32));
        if ((v >= IOU_THRESH) || lq) atomicAdd(&cntsL[bestj], 1);
    }
    __syncthreads();

    // ---- epilogue: one thread per bucket GT row, write the 4 output chunks.
    for (int j = tid; j < cg_; j += 256) {
        int m = glistS[j];
        int i = b * MM + m;
        int take = min(cntsL[j], KK);
        float4 rows, cols, valid, sel;
        rows.x = (0 < take) ? (float)tiL[j * KK + 0] : -1.0f;
        rows.y = (1 < take) ? (float)tiL[j * KK + 1] : -1.0f;
        rows.z = (2 < take) ? (float)tiL[j * KK + 2] : -1.0f;
        rows.w = (3 < take) ? (float)tiL[j * KK + 3] : -1.0f;
        cols.x = (0 < take) ? (float)m : -1.0f;
        cols.y = (1 < take) ? (float)m : -1.0f;
        cols.z = (2 < take) ? (float)m : -1.0f;
        cols.w = (3 < take) ? (float)m : -1.0f;
        valid.x = (0 < take) ? 1.0f : 0.0f;
        valid.y = (1 < take) ? 1.0f : 0.0f;
        valid.z = (2 < take) ? 1.0f : 0.0f;
        valid.w = (3 < take) ? 1.0f : 0.0f;
        sel.x = (0 < take) ? tvL[j * KK + 0] : 0.0f;
        sel.y = (1 < take) ? tvL[j * KK + 1] : 0.0f;
        sel.z = (2 < take) ? tvL[j * KK + 2] : 0.0f;
        sel.w = (3 < take) ? tvL[j * KK + 3] : 0.0f;
        float4* o = (float4*)out;
        const int CH4 = BB * MM;  // 4800 float4s per chunk
        o[0 * CH4 + i] = rows;
        o[1 * CH4 + i] = cols;
        o[2 * CH4 + i] = valid;
        o[3 * CH4 + i] = sel;
    }
}

extern "C" void kernel_launch(void* const* d_in, const int* in_sizes, int n_in,
                              void* d_out, int out_size, void* d_ws, size_t ws_size,
                              hipStream_t stream) {
    // inputs: 0 pred_logits_match (unused), 1 pred_boxes (unused),
    //         2 init_reference (proposals), 3 prompt_inds, 4 gt_labels,
    //         5 gt_boxes, 6 max_k (==4, hardcoded)
    const float4* props = (const float4*)d_in[2];
    const int*    pinds = (const int*)d_in[3];
    const int*    glab  = (const int*)d_in[4];
    const float4* gbox  = (const float4*)d_in[5];
    float* out = (float*)d_out;

    // ws layout (~131 KB):
    char* w = (char*)d_ws;
    int*   pstart = (int*)w;                 w += BB * LL * sizeof(int);      //  5120
    int*   pcnt   = (int*)w;                 w += BB * LL * sizeof(int);      //  5120
    int*   gstart = (int*)w;                 w += BB * LL * sizeof(int);      //  5120
    int*   gcnt   = (int*)w;                 w += BB * LL * sizeof(int);      //  5120
    unsigned short* pidx = (unsigned short*)w; w += BB * NN * sizeof(short);  // 96000
    unsigned short* gidx = (unsigned short*)w;                                //  9600

    kPrep<<<BB, 512, 0, stream>>>(pinds, glab, pidx, pstart, pcnt,
                                  gidx, gstart, gcnt);
    kBuck<<<dim3(LL, BB), 256, 0, stream>>>(props, gbox, pidx, pstart, pcnt,
                                            gidx, gstart, gcnt, out);
}

// Round 5
// 78.531 us; speedup vs baseline: 1.0631x; 1.0631x over previous
//
#include <hip/hip_runtime.h>

// Problem constants (fixed by setup_inputs): B=16, N=3000, M=300, L=80, K=4
#define BB 16
#define NN 3000
#define MM 300
#define LL 80
#define KK 4
#define IOU_THRESH 0.6f

typedef unsigned long long u64;

struct Box { float x1, y1, x2, y2, area; };

__device__ __forceinline__ Box to_xyxy(float4 b) {
#pragma clang fp contract(off)
    Box r;
    r.x1 = b.x - 0.5f * b.z;
    r.y1 = b.y - 0.5f * b.w;
    r.x2 = b.x + 0.5f * b.z;
    r.y2 = b.y + 0.5f * b.w;
    r.area = (r.x2 - r.x1) * (r.y2 - r.y1);
    return r;
}

// Same inlined function used in both the top phase and the asn phase (the
// lq test relies on bitwise-identical iou; same argument order everywhere).
__device__ __forceinline__ float pair_iou(Box a, Box b) {
#pragma clang fp contract(off)
    float ltx = fmaxf(a.x1, b.x1);
    float lty = fmaxf(a.y1, b.y1);
    float rbx = fminf(a.x2, b.x2);
    float rby = fminf(a.y2, b.y2);
    float wx = fmaxf(rbx - ltx, 0.0f);
    float wy = fmaxf(rby - lty, 0.0f);
    float inter = wx * wy;
    float uni = a.area + b.area - inter;
    return inter / fmaxf(uni, 1e-9f);
}

// monotonic float <-> u32 (order-preserving bijection, finite values)
__device__ __forceinline__ unsigned int f32_to_ordered(float f) {
    unsigned int u = __float_as_uint(f);
    return (u & 0x80000000u) ? ~u : (u | 0x80000000u);
}
__device__ __forceinline__ float ordered_to_f32(unsigned int u) {
    unsigned int b = (u & 0x80000000u) ? (u & 0x7FFFFFFFu) : ~u;
    return __uint_as_float(b);
}

__device__ __forceinline__ u64 umax64(u64 a, u64 b) { return a > b ? a : b; }
__device__ __forceinline__ u64 umin64(u64 a, u64 b) { return a < b ? a : b; }

__device__ __forceinline__ u64 shfl_xor_u64(u64 v, int mask) {
    int lo = __shfl_xor((int)(unsigned)v, mask, 64);
    int hi = __shfl_xor((int)(unsigned)(v >> 32), mask, 64);
    return ((u64)(unsigned)hi << 32) | (u64)(unsigned)lo;
}

// branchless insert of k into sorted-desc 4-list
__device__ __forceinline__ void topins(u64 t[4], u64 k) {
    u64 c0 = umin64(t[0], k);
    t[0] = umax64(t[0], k);
    u64 c1 = umin64(t[1], c0);
    t[1] = umax64(t[1], c0);
    u64 c2 = umin64(t[2], c1);
    t[2] = umax64(t[2], c1);
    t[3] = umax64(t[3], c2);
}

// butterfly: top-4 of the union of all 64 lanes' sorted-desc 4-lists (all lanes get result)
__device__ __forceinline__ void wave_merge_top4(u64 t[4]) {
    #pragma unroll
    for (int s = 1; s < 64; s <<= 1) {
        u64 b0 = shfl_xor_u64(t[0], s);
        u64 b1 = shfl_xor_u64(t[1], s);
        u64 b2 = shfl_xor_u64(t[2], s);
        u64 b3 = shfl_xor_u64(t[3], s);
        u64 a0 = t[0], a1 = t[1], a2 = t[2], a3 = t[3];
        t[0] = umax64(a0, b0);
        t[1] = umax64(umin64(a0, b0), umax64(a1, b1));
        t[2] = umax64(umax64(a2, b2), umax64(umin64(a0, b1), umin64(a1, b0)));
        t[3] = umax64(umax64(a3, b3),
               umax64(umin64(a0, b2), umax64(umin64(a1, b1), umin64(a2, b0))));
    }
}

// ===========================================================================
// kFused: ONE block per (label, batch) bucket — grid (80, 16), 256 threads.
// Single dispatch (measured: each extra dispatch costs ~2.9us; the ~81us
// floor is harness fill+sync). The pipeline's dataflow is confined to a
// (b,l) bucket, so bin -> top -> asn -> epilogue run inside the block with
// __syncthreads() only. Changes vs the R3-verified version (both previously
// harness-verified):
//   - binning scans use int4 loads (4 labels per load; NN,MM divisible by 4,
//     per-batch offsets 16B-aligned)
//   - GT xyxy/area staged in LDS by the top phase; asn reuses the exact same
//     bits (R4-verified), preserving the iou==gmax exactness invariant.
// Every (b,m) output slot is written exactly once, by the unique bucket
// (glab[b][m], b). Bucket list order is nondeterministic (LDS atomic
// cursors) but all results are order-invariant (exact u64-key max with
// global-index tie-breaks).
// d_out layout: 4 chunks of BB*MM float4: rows | cols | valid | sel.
// ===========================================================================
__global__ __launch_bounds__(256) void kFused(
    const float4* __restrict__ props, const int* __restrict__ pinds,
    const int* __restrict__ glab, const float4* __restrict__ gbox,
    float* __restrict__ out)
{
    const int l = blockIdx.x;   // label
    const int b = blockIdx.y;   // batch
    const int tid = threadIdx.x;

    __shared__ unsigned short plist[NN];   // proposal indices of this bucket
    __shared__ unsigned short glist[MM];   // GT row indices of this bucket
    __shared__ float4 gxyS[MM];            // staged GT xyxy (bits from top phase)
    __shared__ float  gareaS[MM];          // staged GT area
    __shared__ float  gmaxL[MM];           // per-bucket-row gmax
    __shared__ float  tvL[MM * KK];        // per-bucket-row top-4 values
    __shared__ int    tiL[MM * KK];        // per-bucket-row top-4 indices
    __shared__ int    cntsL[MM];           // per-bucket-row pos counts
    __shared__ int pcur, gcur;

    if (tid == 0) { pcur = 0; gcur = 0; }
    for (int j = tid; j < MM; j += 256) cntsL[j] = 0;
    __syncthreads();

    // ---- bin: GT rows of this bucket (75 int4 loads over 300 labels)
    {
        const int4* gl4 = (const int4*)(glab + b * MM);
        for (int i = tid; i < MM / 4; i += 256) {
            int4 v = gl4[i];
            int base = i * 4;
            if (v.x == l) glist[atomicAdd(&gcur, 1)] = (unsigned short)(base + 0);
            if (v.y == l) glist[atomicAdd(&gcur, 1)] = (unsigned short)(base + 1);
            if (v.z == l) glist[atomicAdd(&gcur, 1)] = (unsigned short)(base + 2);
            if (v.w == l) glist[atomicAdd(&gcur, 1)] = (unsigned short)(base + 3);
        }
    }
    __syncthreads();
    const int cg_ = gcur;
    if (cg_ == 0) return;   // no GT rows with this label -> no outputs owned

    // ---- bin: proposals of this bucket (750 int4 loads over 3000 inds; the
    //      12 KB pinds slice is shared across the 80 blocks of this batch via L2)
    {
        const int4* pi4 = (const int4*)(pinds + b * NN);
        for (int i = tid; i < NN / 4; i += 256) {
            int4 v = pi4[i];
            int base = i * 4;
            if (v.x == l) plist[atomicAdd(&pcur, 1)] = (unsigned short)(base + 0);
            if (v.y == l) plist[atomicAdd(&pcur, 1)] = (unsigned short)(base + 1);
            if (v.z == l) plist[atomicAdd(&pcur, 1)] = (unsigned short)(base + 2);
            if (v.w == l) plist[atomicAdd(&pcur, 1)] = (unsigned short)(base + 3);
        }
    }
    __syncthreads();
    const int cp_ = pcur;

    // ---- top: one wave per bucket GT row. Exact lax.top_k top-4 (value desc,
    //      min-index tie-break) + gmax. Slots beyond cp_ stay at init and are
    //      always masked downstream (take <= counts <= cp_).
    {
        const int lane = tid & 63;
        const int wv = tid >> 6;
        for (int j = wv; j < cg_; j += 4) {
            int m = glist[j];
            Box gt = to_xyxy(gbox[b * MM + m]);
            const u64 init = ((u64)f32_to_ordered(-1.0f) << 32);
            u64 t[4] = {init, init, init, init};
            for (int i = lane; i < cp_; i += 64) {   // cp_ ~ 37, one pass
                int n = plist[i];
                Box pb = to_xyxy(props[(size_t)b * NN + n]);
                float iou = pair_iou(gt, pb);        // all bucket entries match
                u64 key = ((u64)f32_to_ordered(iou) << 32) |
                          (u64)(0xFFFFFFFFu - (unsigned)n);
                topins(t, key);
            }
            wave_merge_top4(t);
            if (lane == 0) {
                #pragma unroll
                for (int q = 0; q < KK; ++q) {
                    tvL[j * KK + q] = ordered_to_f32((unsigned)(t[q] >> 32));
                    tiL[j * KK + q] = (int)(0xFFFFFFFFu - (unsigned)t[q]);
                }
                gmaxL[j] = ordered_to_f32((unsigned)(t[0] >> 32));
                gxyS[j] = make_float4(gt.x1, gt.y1, gt.x2, gt.y2);
                gareaS[j] = gt.area;
            }
        }
    }
    __syncthreads();

    // ---- asn: one thread per bucket proposal. best_gt = argmax over bucket
    //      GT rows with min-global-m tie-break (matches argmax over all M rows:
    //      non-matching rows are -1 < any iou >= 0); lq via exact iou == gmax
    //      (same stored bits, same pair_iou arg order as the top phase).
    for (int p = tid; p < cp_; p += 256) {
        int n = plist[p];
        Box pb = to_xyxy(props[(size_t)b * NN + n]);
        u64 key = 0;
        int bestj = 0;
        bool lq = false;
        for (int j = 0; j < cg_; ++j) {
            float4 q = gxyS[j];
            Box a; a.x1 = q.x; a.y1 = q.y; a.x2 = q.z; a.y2 = q.w; a.area = gareaS[j];
            float iou = pair_iou(a, pb);
            int m = glist[j];
            u64 k = ((u64)f32_to_ordered(iou) << 32) |
                    (u64)(0xFFFFFFFFu - (unsigned)m);
            if (k > key) { key = k; bestj = j; }  // distinct m -> never equal
            lq = lq || (iou == gmaxL[j]);
        }
        // cg_ >= 1 so key was set (iou >= 0 -> k >= 2^63 > 0)
        float v = ordered_to_f32((unsigned)(key >> 32));
        if ((v >= IOU_THRESH) || lq) atomicAdd(&cntsL[bestj], 1);
    }
    __syncthreads();

    // ---- epilogue: one thread per bucket GT row, write the 4 output chunks.
    for (int j = tid; j < cg_; j += 256) {
        int m = glist[j];
        int i = b * MM + m;
        int take = min(cntsL[j], KK);
        float4 rows, cols, valid, sel;
        rows.x = (0 < take) ? (float)tiL[j * KK + 0] : -1.0f;
        rows.y = (1 < take) ? (float)tiL[j * KK + 1] : -1.0f;
        rows.z = (2 < take) ? (float)tiL[j * KK + 2] : -1.0f;
        rows.w = (3 < take) ? (float)tiL[j * KK + 3] : -1.0f;
        cols.x = (0 < take) ? (float)m : -1.0f;
        cols.y = (1 < take) ? (float)m : -1.0f;
        cols.z = (2 < take) ? (float)m : -1.0f;
        cols.w = (3 < take) ? (float)m : -1.0f;
        valid.x = (0 < take) ? 1.0f : 0.0f;
        valid.y = (1 < take) ? 1.0f : 0.0f;
        valid.z = (2 < take) ? 1.0f : 0.0f;
        valid.w = (3 < take) ? 1.0f : 0.0f;
        sel.x = (0 < take) ? tvL[j * KK + 0] : 0.0f;
        sel.y = (1 < take) ? tvL[j * KK + 1] : 0.0f;
        sel.z = (2 < take) ? tvL[j * KK + 2] : 0.0f;
        sel.w = (3 < take) ? tvL[j * KK + 3] : 0.0f;
        float4* o = (float4*)out;
        const int CH4 = BB * MM;  // 4800 float4s per chunk
        o[0 * CH4 + i] = rows;
        o[1 * CH4 + i] = cols;
        o[2 * CH4 + i] = valid;
        o[3 * CH4 + i] = sel;
    }
}

extern "C" void kernel_launch(void* const* d_in, const int* in_sizes, int n_in,
                              void* d_out, int out_size, void* d_ws, size_t ws_size,
                              hipStream_t stream) {
    // inputs: 0 pred_logits_match (unused), 1 pred_boxes (unused),
    //         2 init_reference (proposals), 3 prompt_inds, 4 gt_labels,
    //         5 gt_boxes, 6 max_k (==4, hardcoded)
    const float4* props = (const float4*)d_in[2];
    const int*    pinds = (const int*)d_in[3];
    const int*    glab  = (const int*)d_in[4];
    const float4* gbox  = (const float4*)d_in[5];
    float* out = (float*)d_out;

    kFused<<<dim3(LL, BB), 256, 0, stream>>>(props, pinds, glab, gbox, out);
}